// Round 4
// baseline (600.215 us; speedup 1.0000x reference)
//
#include <hip/hip_runtime.h>

#define NN 8192
#define FD 512
#define CAP 256

__device__ __forceinline__ unsigned f2bf(float x) {  // RNE fp32 -> bf16 bits
  unsigned u = __float_as_uint(x);
  u += 0x7FFFu + ((u >> 16) & 1u);
  return u >> 16;
}

__device__ __forceinline__ int flt2key(float f) {    // order-preserving float->int
  int i = __float_as_int(f);
  return i >= 0 ? i : (i ^ 0x7FFFFFFF);
}
__device__ __forceinline__ float key2flt(int k) {
  return __int_as_float(k >= 0 ? k : (k ^ 0x7FFFFFFF));
}

// K0: idx == arange check -> flag ; init gkey to -FLT_MAX keys
__global__ __launch_bounds__(256) void k0_check(
    const int* __restrict__ idx, int* __restrict__ flag, int* __restrict__ gkey) {
  const int t = blockIdx.x * 256 + threadIdx.x;   // 2048 threads, 1 int4 each
  if (blockIdx.x == 0 && threadIdx.x == 0) {
    gkey[0] = flt2key(-3.4e38f);
    gkey[1] = flt2key(-3.4e38f);
  }
  int4 v = ((const int4*)idx)[t];
  const int base = t * 4;
  bool bad = (v.x != base) | (v.y != base + 1) | (v.z != base + 2) | (v.w != base + 3);
  if (__ballot(bad)) { if ((threadIdx.x & 63) == 0) atomicOr(flag, 1); }
}

// K1: HW[n,o] packed bf16x2 (k innermost); c1[k,n]; c2p[n*2+k]; global max of c2 per head.
// grid 512: k = b&1, 32 rows/block, 8 rows/wave, lane = o
__global__ __launch_bounds__(256) void k1_hw(
    const float* __restrict__ H, const float* __restrict__ W,
    const float* __restrict__ a1, const float* __restrict__ a2,
    unsigned short* __restrict__ hw2, float* __restrict__ c1, float* __restrict__ c2p,
    int* __restrict__ gkey) {
  const int k    = blockIdx.x & 1;
  const int wv   = threadIdx.x >> 6;
  const int lane = threadIdx.x & 63;
  const int nbase = __builtin_amdgcn_readfirstlane((blockIdx.x >> 1) * 32 + wv * 8);
  const float* __restrict__ Wk = W + k * (FD * 64);
  float acc[8] = {0.f,0.f,0.f,0.f,0.f,0.f,0.f,0.f};
  for (int f = 0; f < FD; f += 4) {
    float w0 = Wk[(f+0)*64 + lane];
    float w1 = Wk[(f+1)*64 + lane];
    float w2 = Wk[(f+2)*64 + lane];
    float w3 = Wk[(f+3)*64 + lane];
#pragma unroll
    for (int r = 0; r < 8; ++r) {
      float4 h = *(const float4*)(H + (size_t)(nbase + r) * FD + f);  // wave-uniform
      acc[r] = fmaf(h.x, w0, acc[r]);
      acc[r] = fmaf(h.y, w1, acc[r]);
      acc[r] = fmaf(h.z, w2, acc[r]);
      acc[r] = fmaf(h.w, w3, acc[r]);
    }
  }
  const float a1v = a1[k*64 + lane];
  const float a2v = a2[k*64 + lane];
  float wmax = -3.4e38f;
#pragma unroll
  for (int r = 0; r < 8; ++r) {
    const int n = nbase + r;
    hw2[((size_t)n * 64 + lane) * 2 + k] = (unsigned short)f2bf(acc[r]);
    float t1 = acc[r] * a1v;
    float t2 = acc[r] * a2v;
#pragma unroll
    for (int off = 32; off; off >>= 1) {
      t1 += __shfl_down(t1, off);
      t2 += __shfl_down(t2, off);
    }
    if (lane == 0) {
      c1[k*NN + n] = t1;
      c2p[n*2 + k] = t2;
      wmax = fmaxf(wmax, t2);
    }
  }
  if (lane == 0) atomicMax(&gkey[k], flt2key(wmax));
}

// K2: one wave per row j. All loads coalesced (A strip + packed c2p strip);
// per-slot work is register-only: 2 independent exps + fma. Global-max M (no
// online rescale). Nonzeros -> bucket edge write via colcnt atomic.
__global__ __launch_bounds__(256) void k2_stats(
    const float* __restrict__ A, const int* __restrict__ idx, const int* __restrict__ flag,
    const int* __restrict__ gkey,
    const float* __restrict__ c1, const float* __restrict__ c2p,
    int* __restrict__ colcnt, int* __restrict__ edges, float4* __restrict__ param2) {
  const int wv = threadIdx.x >> 6, lane = threadIdx.x & 63;
  const int j = blockIdx.x * 4 + wv;
  const bool fast = (flag[0] == 0);  // uniform
  const float c10 = c1[j];
  const float c11 = c1[NN + j];
  float M0 = c10 + key2flt(gkey[0]); M0 = (M0 >= 0.f) ? M0 : 0.2f * M0;
  float M1 = c11 + key2flt(gkey[1]); M1 = (M1 >= 0.f) ? M1 : 0.2f * M1;
  const float* __restrict__ Arow = A + (size_t)j * NN;
  float s0 = 0.f, s1 = 0.f;

  for (int g = 0; g < 32; g += 4) {
    float4 a[4], cA[4], cB[4];
    if (fast) {
#pragma unroll
      for (int u = 0; u < 4; ++u) {
        const int cb = (g + u) * 256 + lane * 4;
        a[u]  = *(const float4*)(Arow + cb);
        cA[u] = *(const float4*)(c2p + cb * 2);      // cols cb, cb+1 (h0,h1 pairs)
        cB[u] = *(const float4*)(c2p + cb * 2 + 4);  // cols cb+2, cb+3
      }
    } else {
#pragma unroll
      for (int u = 0; u < 4; ++u) {
        const int cb = (g + u) * 256 + lane * 4;
        a[u].x = Arow[idx[cb+0]];
        a[u].y = Arow[idx[cb+1]];
        a[u].z = Arow[idx[cb+2]];
        a[u].w = Arow[idx[cb+3]];
        cA[u] = *(const float4*)(c2p + cb * 2);
        cB[u] = *(const float4*)(c2p + cb * 2 + 4);
      }
    }
#pragma unroll
    for (int u = 0; u < 4; ++u) {
      const int cb = (g + u) * 256 + lane * 4;
      const float av[4]   = {a[u].x, a[u].y, a[u].z, a[u].w};
      const float c2h0[4] = {cA[u].x, cA[u].z, cB[u].x, cB[u].z};
      const float c2h1[4] = {cA[u].y, cA[u].w, cB[u].y, cB[u].w};
#pragma unroll
      for (int q = 0; q < 4; ++q) {
        if (av[q] != 0.f) {
          const int i = cb + q;
          const int pos = atomicAdd(&colcnt[i], 1);
          if (pos < CAP) edges[(size_t)i * CAP + pos] = j;
          float v0 = c10 + c2h0[q]; v0 = (v0 >= 0.f) ? v0 : 0.2f * v0;
          s0 += __expf(v0 - M0);
          float v1 = c11 + c2h1[q]; v1 = (v1 >= 0.f) ? v1 : 0.2f * v1;
          s1 += __expf(v1 - M1);
        }
      }
    }
  }
#pragma unroll
  for (int off = 32; off; off >>= 1) {
    s0 += __shfl_down(s0, off);
    s1 += __shfl_down(s1, off);
  }
  if (lane == 0) {
    const float I0 = (s0 > 0.f) ? 1.f / s0 : 0.f;
    const float I1 = (s1 > 0.f) ? 1.f / s1 : 0.f;
    param2[j*2 + 0] = make_float4(c10, (s0 > 0.f) ? M0 : 0.f, I0, 0.f);
    param2[j*2 + 1] = make_float4(c11, (s1 > 0.f) ? M1 : 0.f, I1, 0.f);
  }
}

// K3: one wave per output row i (lane = o). Edge indices readfirstlane'd ->
// scalar-path param loads; packed bf16x2 hw covers both heads in one dword.
__global__ __launch_bounds__(256) void k3_aggregate(
    const int* __restrict__ colcnt, const int* __restrict__ edges,
    const float4* __restrict__ param2, const float* __restrict__ c2p,
    const unsigned* __restrict__ hw2, const float* __restrict__ b,
    float* __restrict__ out) {
  const int lane = threadIdx.x & 63;
  const int i = __builtin_amdgcn_readfirstlane(blockIdx.x * 4 + (threadIdx.x >> 6));
  const float c20 = c2p[i*2];
  const float c21 = c2p[i*2 + 1];
  const int cnt = min(colcnt[i], CAP);
  const int* __restrict__ eb = edges + (size_t)i * CAP;
  float acc0 = 0.f, acc1 = 0.f;
  int e = 0;
  for (; e + 4 <= cnt; e += 4) {
    const int4 jv = *(const int4*)(eb + e);
    const int ja = __builtin_amdgcn_readfirstlane(jv.x);
    const int jb = __builtin_amdgcn_readfirstlane(jv.y);
    const int jc = __builtin_amdgcn_readfirstlane(jv.z);
    const int jd = __builtin_amdgcn_readfirstlane(jv.w);
    const float4 pa0 = param2[ja*2], pa1 = param2[ja*2+1];
    const float4 pb0 = param2[jb*2], pb1 = param2[jb*2+1];
    const float4 pc0 = param2[jc*2], pc1 = param2[jc*2+1];
    const float4 pd0 = param2[jd*2], pd1 = param2[jd*2+1];
    const unsigned ua = hw2[ja * 64 + lane];
    const unsigned ub = hw2[jb * 64 + lane];
    const unsigned uc = hw2[jc * 64 + lane];
    const unsigned ud = hw2[jd * 64 + lane];
    float v, w;
    v = pa0.x + c20; v = (v >= 0.f) ? v : 0.2f*v; w = __expf(v - pa0.y) * pa0.z;
    acc0 = fmaf(w, __uint_as_float(ua << 16), acc0);
    v = pa1.x + c21; v = (v >= 0.f) ? v : 0.2f*v; w = __expf(v - pa1.y) * pa1.z;
    acc1 = fmaf(w, __uint_as_float(ua & 0xFFFF0000u), acc1);
    v = pb0.x + c20; v = (v >= 0.f) ? v : 0.2f*v; w = __expf(v - pb0.y) * pb0.z;
    acc0 = fmaf(w, __uint_as_float(ub << 16), acc0);
    v = pb1.x + c21; v = (v >= 0.f) ? v : 0.2f*v; w = __expf(v - pb1.y) * pb1.z;
    acc1 = fmaf(w, __uint_as_float(ub & 0xFFFF0000u), acc1);
    v = pc0.x + c20; v = (v >= 0.f) ? v : 0.2f*v; w = __expf(v - pc0.y) * pc0.z;
    acc0 = fmaf(w, __uint_as_float(uc << 16), acc0);
    v = pc1.x + c21; v = (v >= 0.f) ? v : 0.2f*v; w = __expf(v - pc1.y) * pc1.z;
    acc1 = fmaf(w, __uint_as_float(uc & 0xFFFF0000u), acc1);
    v = pd0.x + c20; v = (v >= 0.f) ? v : 0.2f*v; w = __expf(v - pd0.y) * pd0.z;
    acc0 = fmaf(w, __uint_as_float(ud << 16), acc0);
    v = pd1.x + c21; v = (v >= 0.f) ? v : 0.2f*v; w = __expf(v - pd1.y) * pd1.z;
    acc1 = fmaf(w, __uint_as_float(ud & 0xFFFF0000u), acc1);
  }
  for (; e < cnt; ++e) {
    const int j = __builtin_amdgcn_readfirstlane(eb[e]);
    const float4 p0 = param2[j*2], p1 = param2[j*2+1];
    const unsigned u = hw2[j * 64 + lane];
    float v0 = p0.x + c20; v0 = (v0 >= 0.f) ? v0 : 0.2f*v0;
    float w0 = __expf(v0 - p0.y) * p0.z;
    float v1 = p1.x + c21; v1 = (v1 >= 0.f) ? v1 : 0.2f*v1;
    float w1 = __expf(v1 - p1.y) * p1.z;
    acc0 = fmaf(w0, __uint_as_float(u << 16), acc0);
    acc1 = fmaf(w1, __uint_as_float(u & 0xFFFF0000u), acc1);
  }
  out[(size_t)i * 128 + lane]      = fmaxf(acc0 + b[lane], 0.f);
  out[(size_t)i * 128 + 64 + lane] = fmaxf(acc1 + b[64 + lane], 0.f);
}

extern "C" void kernel_launch(void* const* d_in, const int* in_sizes, int n_in,
                              void* d_out, int out_size, void* d_ws, size_t ws_size,
                              hipStream_t stream) {
  const float* H   = (const float*)d_in[0];
  const float* A   = (const float*)d_in[1];
  const int*   idx = (const int*)d_in[2];
  const float* W   = (const float*)d_in[3];
  const float* b   = (const float*)d_in[4];
  const float* a1  = (const float*)d_in[5];
  const float* a2  = (const float*)d_in[6];
  float* out = (float*)d_out;

  char* ws = (char*)d_ws;
  unsigned short* hw2    = (unsigned short*)(ws + 0);  //  2,097,152 B (bf16x2 packed)
  float*          c1     = (float*)(ws + 2097152);     //     65,536 B
  float*          c2p    = (float*)(ws + 2162688);     //     65,536 B (float2-packed heads)
  float4*         param2 = (float4*)(ws + 2228224);    //    262,144 B
  int*            colcnt = (int*)(ws + 2490368);       //     32,768 B
  int*            flag   = (int*)(ws + 2523136);       //          4 B
  int*            gkey   = (int*)(ws + 2523140);       //          8 B
  int*            edges  = (int*)(ws + 2523392);       //  8,388,608 B (8192 x CAP)

  hipMemsetAsync(colcnt, 0, NN * sizeof(int) + sizeof(int), stream);  // colcnt + flag
  k0_check<<<8, 256, 0, stream>>>(idx, flag, gkey);
  k1_hw<<<512, 256, 0, stream>>>(H, W, a1, a2, hw2, c1, c2p, gkey);
  k2_stats<<<NN / 4, 256, 0, stream>>>(A, idx, flag, gkey, c1, c2p, colcnt, edges, param2);
  k3_aggregate<<<NN / 4, 256, 0, stream>>>(colcnt, edges, param2, c2p, (const unsigned*)hw2, b, out);
}

// Round 5
// 565.203 us; speedup vs baseline: 1.0619x; 1.0619x over previous
//
#include <hip/hip_runtime.h>

#define NN 8192
#define FD 512
typedef unsigned long long u64;

__device__ __forceinline__ unsigned f2bf(float x) {  // RNE fp32 -> bf16 bits
  unsigned u = __float_as_uint(x);
  u += 0x7FFFu + ((u >> 16) & 1u);
  return u >> 16;
}

__device__ __forceinline__ int flt2key(float f) {    // order-preserving float->int
  int i = __float_as_int(f);
  return i >= 0 ? i : (i ^ 0x7FFFFFFF);
}
__device__ __forceinline__ float key2flt(int k) {
  return __int_as_float(k >= 0 ? k : (k ^ 0x7FFFFFFF));
}

// K0: idx == arange check -> flag ; init gkey to -FLT_MAX keys
__global__ __launch_bounds__(256) void k0_check(
    const int* __restrict__ idx, int* __restrict__ flag, int* __restrict__ gkey) {
  const int t = blockIdx.x * 256 + threadIdx.x;   // 2048 threads, 1 int4 each
  if (blockIdx.x == 0 && threadIdx.x == 0) {
    gkey[0] = flt2key(-3.4e38f);
    gkey[1] = flt2key(-3.4e38f);
  }
  int4 v = ((const int4*)idx)[t];
  const int base = t * 4;
  bool bad = (v.x != base) | (v.y != base + 1) | (v.z != base + 2) | (v.w != base + 3);
  if (__ballot(bad)) { if ((threadIdx.x & 63) == 0) atomicOr(flag, 1); }
}

// K1: HW packed bf16x2 (k innermost); c1[k,n]; c2p[n*2+k]; global max of c2 per head.
__global__ __launch_bounds__(256) void k1_hw(
    const float* __restrict__ H, const float* __restrict__ W,
    const float* __restrict__ a1, const float* __restrict__ a2,
    unsigned short* __restrict__ hw2, float* __restrict__ c1, float* __restrict__ c2p,
    int* __restrict__ gkey) {
  const int k    = blockIdx.x & 1;
  const int wv   = threadIdx.x >> 6;
  const int lane = threadIdx.x & 63;
  const int nbase = __builtin_amdgcn_readfirstlane((blockIdx.x >> 1) * 32 + wv * 8);
  const float* __restrict__ Wk = W + k * (FD * 64);
  float acc[8] = {0.f,0.f,0.f,0.f,0.f,0.f,0.f,0.f};
  for (int f = 0; f < FD; f += 4) {
    float w0 = Wk[(f+0)*64 + lane];
    float w1 = Wk[(f+1)*64 + lane];
    float w2 = Wk[(f+2)*64 + lane];
    float w3 = Wk[(f+3)*64 + lane];
#pragma unroll
    for (int r = 0; r < 8; ++r) {
      float4 h = *(const float4*)(H + (size_t)(nbase + r) * FD + f);  // wave-uniform -> s_load
      acc[r] = fmaf(h.x, w0, acc[r]);
      acc[r] = fmaf(h.y, w1, acc[r]);
      acc[r] = fmaf(h.z, w2, acc[r]);
      acc[r] = fmaf(h.w, w3, acc[r]);
    }
  }
  const float a1v = a1[k*64 + lane];
  const float a2v = a2[k*64 + lane];
  float wmax = -3.4e38f;
#pragma unroll
  for (int r = 0; r < 8; ++r) {
    const int n = nbase + r;
    hw2[((size_t)n * 64 + lane) * 2 + k] = (unsigned short)f2bf(acc[r]);
    float t1 = acc[r] * a1v;
    float t2 = acc[r] * a2v;
#pragma unroll
    for (int off = 32; off; off >>= 1) {
      t1 += __shfl_down(t1, off);
      t2 += __shfl_down(t2, off);
    }
    if (lane == 0) {
      c1[k*NN + n] = t1;
      c2p[n*2 + k] = t2;
      wmax = fmaxf(wmax, t2);
    }
  }
  if (lane == 0) atomicMax(&gkey[k], flt2key(wmax));
}

// K2: one wave per row j. Pure streaming: coalesced A chunk loads, ballot ->
// one u64 mask word per 64-col chunk, branchless exp-sum (global-max M), skip
// empty chunks. NO atomics, NO scattered stores.
__global__ __launch_bounds__(256) void k2_stats(
    const float* __restrict__ A, const int* __restrict__ idx, const int* __restrict__ flag,
    const int* __restrict__ gkey,
    const float* __restrict__ c1, const float* __restrict__ c2p,
    u64* __restrict__ rmask, float4* __restrict__ param2) {
  const int wv = threadIdx.x >> 6, lane = threadIdx.x & 63;
  const int j = blockIdx.x * 4 + wv;
  const bool fast = (flag[0] == 0);  // uniform
  const float c10 = c1[j];
  const float c11 = c1[NN + j];
  float M0 = c10 + key2flt(gkey[0]); M0 = (M0 >= 0.f) ? M0 : 0.2f * M0;
  float M1 = c11 + key2flt(gkey[1]); M1 = (M1 >= 0.f) ? M1 : 0.2f * M1;
  const float* __restrict__ Arow = A + (size_t)j * NN;
  float s0 = 0.f, s1 = 0.f;

  for (int w0 = 0; w0 < 128; w0 += 8) {
    float a[8];
    float2 cv[8];
    if (fast) {
#pragma unroll
      for (int u = 0; u < 8; ++u) a[u] = Arow[(w0 + u) * 64 + lane];
    } else {
#pragma unroll
      for (int u = 0; u < 8; ++u) a[u] = Arow[idx[(w0 + u) * 64 + lane]];
    }
#pragma unroll
    for (int u = 0; u < 8; ++u)
      cv[u] = *(const float2*)(c2p + ((w0 + u) * 64 + lane) * 2);
#pragma unroll
    for (int u = 0; u < 8; ++u) {
      const u64 bal = __ballot(a[u] != 0.f);
      if (lane == 0) rmask[(size_t)j * 128 + w0 + u] = bal;
      if (bal) {
        float v0 = c10 + cv[u].x; v0 = (v0 >= 0.f) ? v0 : 0.2f * v0;
        float e0 = __expf(v0 - M0);
        float v1 = c11 + cv[u].y; v1 = (v1 >= 0.f) ? v1 : 0.2f * v1;
        float e1 = __expf(v1 - M1);
        const bool on = (a[u] != 0.f);
        s0 += on ? e0 : 0.f;
        s1 += on ? e1 : 0.f;
      }
    }
  }
#pragma unroll
  for (int off = 32; off; off >>= 1) {
    s0 += __shfl_down(s0, off);
    s1 += __shfl_down(s1, off);
  }
  if (lane == 0) {
    const float I0 = (s0 > 0.f) ? 1.f / s0 : 0.f;
    const float I1 = (s1 > 0.f) ? 1.f / s1 : 0.f;
    param2[j*2 + 0] = make_float4(c10, (s0 > 0.f) ? M0 : 0.f, I0, 0.f);
    param2[j*2 + 1] = make_float4(c11, (s1 > 0.f) ? M1 : 0.f, I1, 0.f);
  }
}

// 64x64 bit transpose across a wave: lane r holds row r; after, lane c holds
// word whose bit r = input lane r's bit c.
__device__ __forceinline__ u64 xpose64(u64 x, int lane) {
  const u64 M[6] = {0x00000000FFFFFFFFULL, 0x0000FFFF0000FFFFULL,
                    0x00FF00FF00FF00FFULL, 0x0F0F0F0F0F0F0F0FULL,
                    0x3333333333333333ULL, 0x5555555555555555ULL};
  int d = 32;
#pragma unroll
  for (int s = 0; s < 6; ++s, d >>= 1) {
    u64 y = __shfl_xor(x, d);
    const u64 ML = M[s], MH = ~ML;
    if ((lane & d) == 0) x = (x & ML) | ((y & ML) << d);
    else                 x = (x & MH) | ((y & MH) >> d);
  }
  return x;
}

// kT: bit-transpose rmask (j-major) -> cmask2 (i-major: cmask2[i*128 + jt]).
// Block 512 thr = 8 waves; wave = one i-chunk w, 8 j-tiles; per-lane 64B stores.
__global__ __launch_bounds__(512) void kT(
    const u64* __restrict__ rmask, u64* __restrict__ cmask2) {
  const int wv = threadIdx.x >> 6, lane = threadIdx.x & 63;
  const int w   = blockIdx.x * 8 + wv;   // i-chunk 0..127
  const int jt0 = blockIdx.y * 8;        // j-tile base 0..120
  u64 x[8];
#pragma unroll
  for (int t = 0; t < 8; ++t)
    x[t] = rmask[(size_t)((jt0 + t) * 64 + lane) * 128 + w];
#pragma unroll
  for (int t = 0; t < 8; ++t) x[t] = xpose64(x[t], lane);
  const size_t i = (size_t)w * 64 + lane;
#pragma unroll
  for (int t = 0; t < 8; t += 2) {
    ulonglong2 v; v.x = x[t]; v.y = x[t+1];
    *(ulonglong2*)(cmask2 + i * 128 + jt0 + t) = v;
  }
}

// K3: 2 waves per output row i (lane = o). Wave-uniform bit-walk of the row's
// mask words (scalar loads); per-edge: scalar param loads + one coalesced
// bf16x2 gather covering both heads. LDS combine, fused bias+ReLU+transpose.
__global__ __launch_bounds__(256) void k3_aggregate(
    const u64* __restrict__ cmask2, const float4* __restrict__ param2,
    const float* __restrict__ c2p, const unsigned* __restrict__ hw2,
    const float* __restrict__ b, float* __restrict__ out) {
  __shared__ float red[4][2][64];
  const int wv = threadIdx.x >> 6, lane = threadIdx.x & 63;
  const int half = wv & 1;
  const int i = __builtin_amdgcn_readfirstlane(blockIdx.x * 2 + (wv >> 1));
  const float c20 = c2p[i*2];
  const float c21 = c2p[i*2 + 1];
  const u64* __restrict__ mrow = cmask2 + (size_t)i * 128 + half * 64;
  float acc0 = 0.f, acc1 = 0.f;
  for (int g = 0; g < 64; g += 8) {
    u64 wd[8];
#pragma unroll
    for (int t = 0; t < 8; ++t) wd[t] = mrow[g + t];
#pragma unroll
    for (int t = 0; t < 8; ++t) {
      u64 m = wd[t];
      const int jbase = (half * 64 + g + t) * 64;
      while (m) {
        const int bit = __builtin_ctzll(m);
        m &= m - 1;
        const int j = jbase + bit;            // wave-uniform
        const float4 p0 = param2[j*2], p1 = param2[j*2 + 1];
        const unsigned u = hw2[j * 64 + lane];
        float v0 = p0.x + c20; v0 = (v0 >= 0.f) ? v0 : 0.2f * v0;
        const float w0 = __expf(v0 - p0.y) * p0.z;
        float v1 = p1.x + c21; v1 = (v1 >= 0.f) ? v1 : 0.2f * v1;
        const float w1 = __expf(v1 - p1.y) * p1.z;
        acc0 = fmaf(w0, __uint_as_float(u << 16), acc0);
        acc1 = fmaf(w1, __uint_as_float(u & 0xFFFF0000u), acc1);
      }
    }
  }
  red[wv][0][lane] = acc0;
  red[wv][1][lane] = acc1;
  __syncthreads();
  if (half == 0) {
    acc0 += red[wv + 1][0][lane];
    acc1 += red[wv + 1][1][lane];
    out[(size_t)i * 128 + lane]      = fmaxf(acc0 + b[lane], 0.f);
    out[(size_t)i * 128 + 64 + lane] = fmaxf(acc1 + b[64 + lane], 0.f);
  }
}

extern "C" void kernel_launch(void* const* d_in, const int* in_sizes, int n_in,
                              void* d_out, int out_size, void* d_ws, size_t ws_size,
                              hipStream_t stream) {
  const float* H   = (const float*)d_in[0];
  const float* A   = (const float*)d_in[1];
  const int*   idx = (const int*)d_in[2];
  const float* W   = (const float*)d_in[3];
  const float* b   = (const float*)d_in[4];
  const float* a1  = (const float*)d_in[5];
  const float* a2  = (const float*)d_in[6];
  float* out = (float*)d_out;

  char* ws = (char*)d_ws;
  unsigned short* hw2    = (unsigned short*)(ws + 0);   //  2,097,152 B (bf16x2 packed)
  float*          c1     = (float*)(ws + 2097152);      //     65,536 B
  float*          c2p    = (float*)(ws + 2162688);      //     65,536 B (float2-packed heads)
  float4*         param2 = (float4*)(ws + 2228224);     //    262,144 B
  int*            flag   = (int*)(ws + 2490368);        //          4 B
  int*            gkey   = (int*)(ws + 2490372);        //          8 B
  u64*            rmask  = (u64*)(ws + 2490624);        //  8,388,608 B (j-major bitmask)
  u64*            cmask2 = (u64*)(ws + 10879232);       //  8,388,608 B (i-major bitmask)

  hipMemsetAsync(flag, 0, sizeof(int), stream);
  k0_check<<<8, 256, 0, stream>>>(idx, flag, gkey);
  k1_hw<<<512, 256, 0, stream>>>(H, W, a1, a2, hw2, c1, c2p, gkey);
  k2_stats<<<NN / 4, 256, 0, stream>>>(A, idx, flag, gkey, c1, c2p, rmask, param2);
  kT<<<dim3(16, 16), 512, 0, stream>>>(rmask, cmask2);
  k3_aggregate<<<NN / 2, 256, 0, stream>>>(cmask2, param2, c2p, (const unsigned*)hw2, b, out);
}